// Round 1
// baseline (24.275 us; speedup 1.0000x reference)
//
#include <hip/hip_runtime.h>

// ResampleLayer: linear time-resampling of [B,S,D] embeddings from sorted
// timestamps ts[B,S] onto a uniform grid of OUT_LEN points in [0, 100].
//
// B=32, S=4096, D=256, OUT_LEN=1001, t_l = l * 0.1.
//
// Per output point (b,l): lower_bound into ts[b,:] (first i with ts[i] >= t),
// clip to [1, S-1], then out[b,l,:] = lerp(embed[b,idx-1,:], embed[b,idx,:]).

#define RS_B 32
#define RS_S 4096
#define RS_D 256
#define RS_OUTLEN 1001

__global__ __launch_bounds__(64) void resample_kernel(
    const float* __restrict__ embed,   // [B, S, D]
    const float* __restrict__ ts,      // [B, S] sorted along S
    float* __restrict__ out)           // [B, OUT_LEN, D]
{
    const int bid = blockIdx.x;            // b * OUT_LEN + l
    const int b = bid / RS_OUTLEN;
    const int l = bid - b * RS_OUTLEN;

    // t matches jnp.linspace(0, 100, 1001)[l] == l * 0.1 (computed in double,
    // rounded to f32 — within 1 ulp of linspace; threshold is lenient).
    const float t = (float)((double)l * (100.0 / 1000.0));

    const float* __restrict__ tsr = ts + (size_t)b * RS_S;

    // lower_bound: first i in [0, S] with tsr[i] >= t. All 64 lanes run the
    // identical search (same-address loads broadcast; no LDS needed).
    int lo = 0, hi = RS_S;
    while (lo < hi) {
        int mid = (lo + hi) >> 1;
        float v = tsr[mid];
        if (v < t) lo = mid + 1; else hi = mid;
    }
    int idx = lo;
    if (idx < 1) idx = 1;
    if (idx > RS_S - 1) idx = RS_S - 1;

    const float x_lo = tsr[idx - 1];
    const float x_hi = tsr[idx];
    // slope-form to mirror reference arithmetic: y = (y_hi-y_lo)/(x_hi-x_lo)*(t-x_lo)+y_lo
    const float inv_dx = 1.0f / (x_hi - x_lo);
    const float dt = t - x_lo;

    // Each lane handles one float4 of the D=256 channels (64 * 4 = 256).
    const int d4 = threadIdx.x;
    const float4* __restrict__ ylo =
        (const float4*)(embed + ((size_t)b * RS_S + (size_t)(idx - 1)) * RS_D) + d4;
    const float4* __restrict__ yhi =
        (const float4*)(embed + ((size_t)b * RS_S + (size_t)idx) * RS_D) + d4;

    float4 a = *ylo;
    float4 c = *yhi;
    float4 r;
    r.x = (c.x - a.x) * inv_dx * dt + a.x;
    r.y = (c.y - a.y) * inv_dx * dt + a.y;
    r.z = (c.z - a.z) * inv_dx * dt + a.z;
    r.w = (c.w - a.w) * inv_dx * dt + a.w;

    float4* __restrict__ op =
        (float4*)(out + ((size_t)b * RS_OUTLEN + (size_t)l) * RS_D) + d4;
    *op = r;
}

extern "C" void kernel_launch(void* const* d_in, const int* in_sizes, int n_in,
                              void* d_out, int out_size, void* d_ws, size_t ws_size,
                              hipStream_t stream) {
    const float* embed = (const float*)d_in[0];  // [32, 4096, 256] f32
    const float* ts    = (const float*)d_in[1];  // [32, 4096] f32 sorted
    float* out         = (float*)d_out;          // [32, 1001, 256] f32

    const int nblocks = RS_B * RS_OUTLEN;        // 32032
    resample_kernel<<<nblocks, 64, 0, stream>>>(embed, ts, out);
}

// Round 2
// 22.430 us; speedup vs baseline: 1.0823x; 1.0823x over previous
//
#include <hip/hip_runtime.h>

// ResampleLayer: linear time-resampling of [B,S,D] f32 embeddings from sorted
// timestamps ts[B,S] onto a uniform grid of OUT_LEN points in [0, 100].
//
// B=32, S=4096, D=256, OUT_LEN=1001, t_l = l * 0.1.
//
// Structure: 256-thread blocks (4 waves); each wave owns one output point
// (b, l). The lower_bound into ts[b,:] is a 2-step 64-ary wave-parallel
// search (ballot+popcount) — 2 parallel loads instead of a 12-deep dependent
// binary-search chain. Then each lane lerps one float4 of the D=256 channels.

#define RS_B 32
#define RS_S 4096
#define RS_D 256
#define RS_OUTLEN 1001
#define RS_LPB 4           // output points (waves) per block

__global__ __launch_bounds__(256) void resample_kernel(
    const float* __restrict__ embed,   // [B, S, D]
    const float* __restrict__ ts,      // [B, S] sorted along S
    float* __restrict__ out)           // [B, OUT_LEN, D]
{
    const int b = blockIdx.y;
    const int wave = threadIdx.x >> 6;
    const int lane = threadIdx.x & 63;
    const int l = blockIdx.x * RS_LPB + wave;
    if (l >= RS_OUTLEN) return;

    // t matches jnp.linspace(0, 100, 1001)[l] == l * 0.1 (double-derived,
    // within 1 ulp of linspace; absmax threshold is lenient).
    const float t = (float)((double)l * (100.0 / 1000.0));

    const float* __restrict__ tsr = ts + (size_t)b * RS_S;

    // ---- 64-ary lower_bound: first i in [0, S] with tsr[i] >= t ----
    // Step 1: lane i samples the LAST element of 64-element chunk i.
    // Chunks fully below t have last < t; their count = boundary chunk.
    float s1 = tsr[lane * 64 + 63];
    unsigned long long m1 = __ballot(s1 < t);
    int c = __popcll(m1);                 // 0..64
    int chunk = c < 63 ? c : 63;          // c==64 => whole array < t; chunk 63
                                          // still yields lo = 4096 below.
    // Step 2: scan chunk `chunk` in parallel.
    float s2 = tsr[chunk * 64 + lane];
    unsigned long long m2 = __ballot(s2 < t);
    int lo = chunk * 64 + __popcll(m2);   // exact lower_bound in [0, S]

    int idx = lo;
    if (idx < 1) idx = 1;
    if (idx > RS_S - 1) idx = RS_S - 1;

    const float x_lo = tsr[idx - 1];      // same-address broadcast, L2-hot
    const float x_hi = tsr[idx];
    const float inv_dx = 1.0f / (x_hi - x_lo);
    const float dt = t - x_lo;

    // Each lane handles one float4 of the D=256 channels (64 * 4 = 256).
    const float4* __restrict__ ylo =
        (const float4*)(embed + ((size_t)b * RS_S + (size_t)(idx - 1)) * RS_D) + lane;
    const float4* __restrict__ yhi =
        (const float4*)(embed + ((size_t)b * RS_S + (size_t)idx) * RS_D) + lane;

    float4 a = *ylo;
    float4 cc = *yhi;
    float4 r;
    r.x = (cc.x - a.x) * inv_dx * dt + a.x;
    r.y = (cc.y - a.y) * inv_dx * dt + a.y;
    r.z = (cc.z - a.z) * inv_dx * dt + a.z;
    r.w = (cc.w - a.w) * inv_dx * dt + a.w;

    float4* __restrict__ op =
        (float4*)(out + ((size_t)b * RS_OUTLEN + (size_t)l) * RS_D) + lane;
    *op = r;
}

extern "C" void kernel_launch(void* const* d_in, const int* in_sizes, int n_in,
                              void* d_out, int out_size, void* d_ws, size_t ws_size,
                              hipStream_t stream) {
    const float* embed = (const float*)d_in[0];  // [32, 4096, 256] f32
    const float* ts    = (const float*)d_in[1];  // [32, 4096] f32 sorted
    float* out         = (float*)d_out;          // [32, 1001, 256] f32

    dim3 grid((RS_OUTLEN + RS_LPB - 1) / RS_LPB, RS_B);  // 251 x 32
    resample_kernel<<<grid, 256, 0, stream>>>(embed, ts, out);
}

// Round 3
// 22.051 us; speedup vs baseline: 1.1008x; 1.0172x over previous
//
#include <hip/hip_runtime.h>

// ResampleLayer: linear time-resampling of [B,S,D] f32 embeddings from sorted
// timestamps ts[B,S] onto a uniform grid of OUT_LEN points in [0, 100].
//
// B=32, S=4096, D=256, OUT_LEN=1001, t_l = l * 0.1.
//
// Structure: one 64-thread wave per (b, 16 consecutive l). Lanes run 16
// independent per-lane binary searches (lane&15 -> point; 4x redundant across
// the wave, no divergence). Then an unrolled payload loop: __shfl(_, q) with
// compile-time q folds to v_readlane (scalar broadcast), and each lane lerps
// one float4 of D=256. The 16 iterations' loads are independent -> high MLP.

#define RS_B 32
#define RS_S 4096
#define RS_D 256
#define RS_OUTLEN 1001
#define RS_PPW 16          // output points per wave

__global__ __launch_bounds__(64) void resample_kernel(
    const float* __restrict__ embed,   // [B, S, D]
    const float* __restrict__ ts,      // [B, S] sorted along S
    float* __restrict__ out)           // [B, OUT_LEN, D]
{
    const int b  = blockIdx.y;
    const int l0 = blockIdx.x * RS_PPW;
    const int lane = threadIdx.x;      // 0..63
    const int p = lane & 15;           // which point this lane searches

    int l = l0 + p;
    if (l > RS_OUTLEN - 1) l = RS_OUTLEN - 1;   // clamp; tail results unused
    // t matches jnp.linspace(0, 100, 1001)[l] == l * 0.1 (double-derived).
    const float t = (float)((double)l * (100.0 / 1000.0));

    const float* __restrict__ tsr = ts + (size_t)b * RS_S;

    // Per-lane lower_bound: first i in [0, S] with tsr[i] >= t. 12 fixed
    // steps (S = 2^12). ts row is 16 KB -> L1-resident; <=16 distinct lines
    // per step across the wave.
    int lo = 0, hi = RS_S;
#pragma unroll
    for (int it = 0; it < 12; ++it) {
        int mid = (lo + hi) >> 1;
        float v = tsr[mid];
        if (v < t) lo = mid + 1; else hi = mid;
    }
    int idx = lo;
    if (idx < 1) idx = 1;
    if (idx > RS_S - 1) idx = RS_S - 1;

    const float x_lo = tsr[idx - 1];
    const float x_hi = tsr[idx];
    // single per-point weight: r = a + (c - a) * w1
    const float w1 = (t - x_lo) / (x_hi - x_lo);

    // ---- payload: 16 points, each lane owns one float4 of D=256 ----
    const float4* __restrict__ ebase =
        (const float4*)(embed + (size_t)b * RS_S * RS_D);         // row stride 64 float4
    float4* __restrict__ obase =
        (float4*)(out + ((size_t)b * RS_OUTLEN + (size_t)l0) * RS_D);

#pragma unroll
    for (int q = 0; q < RS_PPW; ++q) {
        if (l0 + q > RS_OUTLEN - 1) break;     // uniform tail exit
        const int   sidx = __shfl(idx, q);     // compile-time q -> v_readlane
        const float sw   = __shfl(w1,  q);

        const float4* plo = ebase + (size_t)(sidx - 1) * (RS_D / 4) + lane;
        const float4* phi = plo + (RS_D / 4);
        float4 a = *plo;
        float4 c = *phi;
        float4 r;
        r.x = a.x + (c.x - a.x) * sw;
        r.y = a.y + (c.y - a.y) * sw;
        r.z = a.z + (c.z - a.z) * sw;
        r.w = a.w + (c.w - a.w) * sw;
        *(obase + (size_t)q * (RS_D / 4) + lane) = r;
    }
}

extern "C" void kernel_launch(void* const* d_in, const int* in_sizes, int n_in,
                              void* d_out, int out_size, void* d_ws, size_t ws_size,
                              hipStream_t stream) {
    const float* embed = (const float*)d_in[0];  // [32, 4096, 256] f32
    const float* ts    = (const float*)d_in[1];  // [32, 4096] f32 sorted
    float* out         = (float*)d_out;          // [32, 1001, 256] f32

    dim3 grid((RS_OUTLEN + RS_PPW - 1) / RS_PPW, RS_B);  // 63 x 32 = 2016 waves
    resample_kernel<<<grid, 64, 0, stream>>>(embed, ts, out);
}